// Round 13
// baseline (832.393 us; speedup 1.0000x reference)
//
#include <hip/hip_runtime.h>
#include <hip/hip_bf16.h>

// y[n,o] = sum_r e[n,r]*(W[r]@x[n])[o] + (e@b)[n,o]
// One bf16 GEMM, K = 8256 with permutation k = il*64 + rh*32 + ih*16 + rl
// (r = rh*16+rl, i = 128*ih + il), bias tile appended (b at ih=0 cols, 0 at ih=1).
// Tile t == il. A'[n,k] = e[n,r]*x[n,i]. Thread (srow, rh) stages 64 CONSECUTIVE
// bytes rh*64+{0,16,32,48} -> R10's conflict-free write shape (R12's split-chunk
// pattern caused 2.58e7 bank conflicts) while needing only er[16] (R12's low VGPR).
// Geometry: 256 thr, 4 waves 2Mx2N, wave tile 64x64, acc[4][4]=64 AGPR, LDS 80 KB
// -> 2 blocks/CU; counted vmcnt(4), tri-buffered B, XOR-swizzled LDS, setprio.

typedef __attribute__((ext_vector_type(4))) float f32x4;
typedef __attribute__((ext_vector_type(8))) short short8;
typedef __attribute__((ext_vector_type(8))) unsigned short ushort8;

#define R_DIM 32
#define I_DIM 256
#define O_DIM 256
#define KW    8192
#define KEXT  8256            // +64: [8192,8224)... bias block, perm'd
#define BM    128
#define BNB   128             // per-block N (2 N-blocks cover O=256)
#define BK    64
#define NT    (KEXT / BK)     // 129
#define NTHR  256

__device__ __forceinline__ unsigned short f2bf(float f) {
  unsigned u = __builtin_bit_cast(unsigned, f);
  u += 0x7FFFu + ((u >> 16) & 1u);  // RNE
  return (unsigned short)(u >> 16);
}

__device__ __forceinline__ unsigned pk2(float a, float b) {
  __hip_bfloat162 h = __float22bfloat162_rn(make_float2(a, b));  // v_cvt_pk_bf16_f32, RNE
  unsigned u;
  __builtin_memcpy(&u, &h, sizeof(u));
  return u;
}

__device__ __forceinline__ void gld_lds16(const void* g, void* l) {
  __builtin_amdgcn_global_load_lds(
      (const __attribute__((address_space(1))) unsigned int*)g,
      (__attribute__((address_space(3))) unsigned int*)l, 16, 0, 0);
}

// ---- prep: Wb[o][k], k = il*64 + rh*32 + ih*16 + rl; bias block appended ----
__global__ void prep_w(const float* __restrict__ W, const float* __restrict__ b,
                       unsigned short* __restrict__ Wb) {
  const int id = blockIdx.x * 256 + threadIdx.x;   // 256 * 2064 threads exactly
  const int o  = id / (KEXT / 4);
  const int k4 = (id - o * (KEXT / 4)) * 4;
  float v[4];
  if (k4 < KW) {
    const int il = k4 >> 6;
    const int c  = k4 & 63;
    const int rh = c >> 5;
    const int ih = (c >> 4) & 1;
    const int rl = c & 15;                 // 0,4,8,12 (k4 is 4-aligned)
    const int i  = 128 * ih + il;
#pragma unroll
    for (int j = 0; j < 4; ++j)
      v[j] = W[((size_t)((rh * 16 + rl + j) * O_DIM + o)) * I_DIM + i];
  } else {
    const int c  = k4 - KW;                // 0..63
    const int ih = (c >> 4) & 1;
    const int rb = ((c >> 5) << 4) | (c & 15);
#pragma unroll
    for (int j = 0; j < 4; ++j)
      v[j] = (ih == 0) ? b[(rb + j) * O_DIM + o] : 0.f;
  }
  uint2 pk;
  pk.x = pk2(v[0], v[1]);
  pk.y = pk2(v[2], v[3]);
  *(uint2*)&Wb[(size_t)o * KEXT + k4] = pk;
}

// ---- main: 256 thr, 4 waves (2M x 2N), wave tile 64x64, 2 blocks/CU ----
__global__ __launch_bounds__(NTHR) void lkg13(
    const float* __restrict__ x, const float* __restrict__ e,
    const unsigned short* __restrict__ Wb, float* __restrict__ out, int Ntot) {
  __shared__ unsigned short Al[2][BM * BK];    // 2 x 16 KB
  __shared__ unsigned short Bl[3][BNB * BK];   // 3 x 16 KB  (80 KB total -> 2 blocks/CU)

  const int tid  = threadIdx.x;
  const int lane = tid & 63;
  const int w    = tid >> 6;     // 0..3
  const int wr   = w >> 1;       // 0..1  (M)
  const int wc   = w & 1;        // 0..1  (N)
  const int l15  = lane & 15;
  const int sx   = (l15 & 7) << 4;
  const int kb0  = (lane >> 4) << 4;

  const int mi = (int)blockIdx.x >> 1;     // M-tile
  const int ni = (int)blockIdx.x & 1;      // N-half
  const int m0 = mi * BM;
  const unsigned short* WbN = Wb + (size_t)(ni * BNB) * KEXT;

  const int srow = tid >> 1;               // 0..127: A row this thread stages
  const int rh   = tid & 1;                // r-half this thread covers
  const int gr   = min(m0 + srow, Ntot - 1);

  // B gld_lds source-side swizzle (rule #21: linear dest + inverse-swz source)
  const int bro = lane >> 3;              // row within 8-row group
  const int bch = (lane & 7) ^ bro;       // pre-swizzled chunk index

  // e r-half in regs: er[j] = e[gr, rh*16 + j], j = 0..15
  float er[16];
#pragma unroll
  for (int p = 0; p < 4; ++p) {
    const float4 ev = *(const float4*)&e[(size_t)gr * R_DIM + rh * 16 + p * 4];
    er[p * 4 + 0] = ev.x; er[p * 4 + 1] = ev.y;
    er[p * 4 + 2] = ev.z; er[p * 4 + 3] = ev.w;
  }
  const float* xr0 = x + (size_t)gr * I_DIM;        // i-half 0 stream (il = t)
  const float* xr1 = x + (size_t)gr * I_DIM + 128;  // i-half 1 stream

  f32x4 acc[4][4];
#pragma unroll
  for (int a = 0; a < 4; ++a)
#pragma unroll
    for (int c = 0; c < 4; ++c) acc[a][c] = (f32x4){0.f, 0.f, 0.f, 0.f};

  auto issueB4 = [&](unsigned short* Bd, int t2) {
    const size_t k0 = (size_t)t2 * BK;
#pragma unroll
    for (int g = 0; g < 4; ++g)
      gld_lds16(WbN + (size_t)(w * 32 + g * 8 + bro) * KEXT + k0 + bch * 8,
                Bd + (w * 32 + g * 8) * BK);
  };
  // stage (srow, rh): 64 consecutive bytes rh*64 + c*16, c=0..3 (each ^sw).
  // chunk c: cols rh*32 + c*8 -> {x0*er[0..7], x0*er[8..15], x1*er[0..7], x1*er[8..15]}
  auto stageA = [&](unsigned short* Ad, float xs0, float xs1) {
    char* rowp = (char*)(Ad + srow * BK);
    const int sw = (srow & 7) << 4;
    const int base = rh * 64;
#pragma unroll
    for (int c = 0; c < 4; ++c) {
      const float xs = (c < 2) ? xs0 : xs1;
      const int eb = (c & 1) * 8;
      uint4 wv;
      wv.x = pk2(xs * er[eb + 0], xs * er[eb + 1]);
      wv.y = pk2(xs * er[eb + 2], xs * er[eb + 3]);
      wv.z = pk2(xs * er[eb + 4], xs * er[eb + 5]);
      wv.w = pk2(xs * er[eb + 6], xs * er[eb + 7]);
      *(uint4*)(rowp + ((base + c * 16) ^ sw)) = wv;
    }
  };
  auto rdA = [&](const unsigned short* Ab, int ks, int fr) -> short8 {
    const int row = wr * 64 + fr * 16 + l15;
    return *(const short8*)((const char*)Ab + row * 128 + ((ks * 64 + kb0) ^ sx));
  };
  auto rdB = [&](const unsigned short* Bb, int ks, int fc) -> short8 {
    const int row = wc * 64 + fc * 16 + l15;
    return *(const short8*)((const char*)Bb + row * 128 + ((ks * 64 + kb0) ^ sx));
  };

  // mode bits: 1 = stage A(t+1) with scales xs0/xs1, 2 = issue B(t+2)
  auto tileF = [&](int t, float xs0, float xs1, int mode, int apar, int cb) {
    const unsigned short* Ac = Al[apar];
    unsigned short*       Aw = Al[apar ^ 1];
    const unsigned short* Bc = Bl[cb];
    unsigned short*       Bw = Bl[cb >= 1 ? cb - 1 : 2];   // (cb+2)%3

    short8 af[4], bf[4];

    // ---- P1: ks0 frag reads (8) + B(t+2) issue ----
#pragma unroll
    for (int fr = 0; fr < 4; ++fr) af[fr] = rdA(Ac, 0, fr);
#pragma unroll
    for (int fc = 0; fc < 4; ++fc) bf[fc] = rdB(Bc, 0, fc);
    if (mode & 2) issueB4(Bw, t + 2);
    __builtin_amdgcn_s_barrier();
    asm volatile("s_waitcnt lgkmcnt(0)" ::: "memory");
    __builtin_amdgcn_s_setprio(1);
#pragma unroll
    for (int fr = 0; fr < 4; ++fr)
#pragma unroll
      for (int fc = 0; fc < 4; ++fc)
        acc[fr][fc] = __builtin_amdgcn_mfma_f32_16x16x32_bf16(af[fr], bf[fc],
                                                              acc[fr][fc], 0, 0, 0);
    __builtin_amdgcn_s_setprio(0);
    __builtin_amdgcn_s_barrier();

    // ---- P2: ks1 frag reads (8) + A(t+1) stage; publish waits; MFMA ----
#pragma unroll
    for (int fr = 0; fr < 4; ++fr) af[fr] = rdA(Ac, 1, fr);
#pragma unroll
    for (int fc = 0; fc < 4; ++fc) bf[fc] = rdB(Bc, 1, fc);
    if (mode & 1) stageA(Aw, xs0, xs1);
    asm volatile("s_waitcnt lgkmcnt(0)" ::: "memory");   // own reads + A-writes drained
    if (mode & 2) {
      asm volatile("s_waitcnt vmcnt(4)" ::: "memory");   // B(t+1) done; B(t+2) in flight
    } else {
      asm volatile("s_waitcnt vmcnt(0)" ::: "memory");   // tail tiles
    }
    __builtin_amdgcn_s_barrier();
    __builtin_amdgcn_s_setprio(1);
#pragma unroll
    for (int fr = 0; fr < 4; ++fr)
#pragma unroll
      for (int fc = 0; fc < 4; ++fc)
        acc[fr][fc] = __builtin_amdgcn_mfma_f32_16x16x32_bf16(af[fr], bf[fc],
                                                              acc[fr][fc], 0, 0, 0);
    __builtin_amdgcn_s_setprio(0);
    __builtin_amdgcn_s_barrier();   // closing barrier: t+1 buffers published
  };

  // ---- prologue: A(0)->Al[0]; B(0)->Bl[0], B(1)->Bl[1] (B(1) stays in flight) ----
  float4 xv0 = *(const float4*)xr0;             // i-half-0 x scalars, tiles 0..3
  float4 xv1 = *(const float4*)xr1;             // i-half-1 x scalars, tiles 0..3
  stageA(Al[0], xv0.x, xv1.x);
  issueB4(Bl[0], 0);
  issueB4(Bl[1], 1);
  asm volatile("s_waitcnt lgkmcnt(0)" ::: "memory");
  asm volatile("s_waitcnt vmcnt(4)" ::: "memory");   // B(0) resident; B(1) in flight
  __builtin_amdgcn_s_barrier();

  int cb = 0;                                    // t % 3
  for (int u = 0; u < 32; ++u) {
    float4 xn0 = xv0, xn1 = xv1;
    if (u < 31) {
      xn0 = *(const float4*)(xr0 + (u + 1) * 4);
      xn1 = *(const float4*)(xr1 + (u + 1) * 4);
    }
    const int t0 = u * 4;
    tileF(t0 + 0, xv0.y, xv1.y, 3, 0, cb); cb = (cb == 2) ? 0 : cb + 1;
    tileF(t0 + 1, xv0.z, xv1.z, 3, 1, cb); cb = (cb == 2) ? 0 : cb + 1;
    tileF(t0 + 2, xv0.w, xv1.w, 3, 0, cb); cb = (cb == 2) ? 0 : cb + 1;
    if (u < 31) {
      tileF(t0 + 3, xn0.x, xn1.x, 3, 1, cb);
    } else {          // t=127: stage bias tile A(128): ih0 cols = er, ih1 cols = 0
      tileF(t0 + 3, 1.f, 0.f, 1, 1, cb);
    }
    cb = (cb == 2) ? 0 : cb + 1;
    xv0 = xn0; xv1 = xn1;
  }
  tileF(128, 0.f, 0.f, 0, 0, cb);   // bias tile: compute only (cb == 128%3 == 2)

  // ---- epilogue: C layout col = lane&15, row = (lane>>4)*4 + j ----
#pragma unroll
  for (int fr = 0; fr < 4; ++fr) {
    const int r0 = m0 + wr * 64 + fr * 16 + (lane >> 4) * 4;
#pragma unroll
    for (int j = 0; j < 4; ++j) {
      const int rr = r0 + j;
      if (rr < Ntot) {
#pragma unroll
        for (int fc = 0; fc < 4; ++fc) {
          const int col = ni * BNB + wc * 64 + fc * 16 + l15;
          out[(size_t)rr * O_DIM + col] = acc[fr][fc][j];
        }
      }
    }
  }
}

// ---- fallback (ws too small): simple 2-barrier kernel reading W/b directly ----
__global__ __launch_bounds__(256) void lkg_fb(
    const float* __restrict__ x, const float* __restrict__ e,
    const float* __restrict__ Wf, const float* __restrict__ bf32,
    float* __restrict__ out, int Ntot) {
  const int FBK = 64;
  const int FNT = (KW + 64) / FBK;
  __shared__ unsigned short Alds[128 * 64];
  __shared__ unsigned short Blds[256 * 64];

  const int tid = threadIdx.x, lane = tid & 63, wid = tid >> 6;
  const int wr = wid >> 1, wc = wid & 1, l15 = lane & 15, lk8 = (lane >> 4) * 8;
  const int m0 = (int)blockIdx.x * 128;
  const int srow = tid >> 1, skq = (tid & 1) * 32;
  const int gr = min(m0 + srow, Ntot - 1);

  f32x4 acc[4][8];
#pragma unroll
  for (int a = 0; a < 4; ++a)
#pragma unroll
    for (int c = 0; c < 8; ++c) acc[a][c] = (f32x4){0.f, 0.f, 0.f, 0.f};

  for (int t = 0; t < FNT; ++t) {
    const int k0 = t * FBK;
    float av[32];
    if (k0 < KW) {
      const int r = k0 >> 8, i0 = k0 & 255;
      const float ev = e[(size_t)gr * R_DIM + r];
#pragma unroll
      for (int p = 0; p < 8; ++p) {
        const float4 xvv = *(const float4*)&x[(size_t)gr * I_DIM + i0 + skq + p * 4];
        av[p * 4 + 0] = xvv.x * ev; av[p * 4 + 1] = xvv.y * ev;
        av[p * 4 + 2] = xvv.z * ev; av[p * 4 + 3] = xvv.w * ev;
      }
    } else {
#pragma unroll
      for (int s2 = 0; s2 < 32; ++s2) {
        const int kk = skq + s2;
        av[s2] = (kk < R_DIM) ? e[(size_t)gr * R_DIM + kk] : 0.f;
      }
    }
    const int bo = tid;
    if (k0 < KW) {
      const int r = k0 >> 8, i0 = k0 & 255;
#pragma unroll
      for (int h = 0; h < 4; ++h) {
        float bv[16];
#pragma unroll
        for (int p = 0; p < 4; ++p) {
          const float4 wv =
              *(const float4*)&Wf[((size_t)(r * O_DIM + bo)) * I_DIM + i0 + h * 16 + p * 4];
          bv[p * 4 + 0] = wv.x; bv[p * 4 + 1] = wv.y;
          bv[p * 4 + 2] = wv.z; bv[p * 4 + 3] = wv.w;
        }
#pragma unroll
        for (int g2 = 0; g2 < 2; ++g2) {
          ushort8 pw;
#pragma unroll
          for (int j = 0; j < 8; ++j) pw[j] = f2bf(bv[g2 * 8 + j]);
          *(ushort8*)&Blds[bo * FBK + h * 16 + g2 * 8] = pw;
        }
      }
    } else {
#pragma unroll
      for (int h = 0; h < 8; ++h) {
        ushort8 pw;
#pragma unroll
        for (int j = 0; j < 8; ++j) {
          const int kk = h * 8 + j;
          pw[j] = (kk < R_DIM) ? f2bf(bf32[kk * O_DIM + bo]) : (unsigned short)0;
        }
        *(ushort8*)&Blds[bo * FBK + h * 8] = pw;
      }
    }
#pragma unroll
    for (int h = 0; h < 4; ++h) {
      ushort8 pw;
#pragma unroll
      for (int j = 0; j < 8; ++j) pw[j] = f2bf(av[h * 8 + j]);
      *(ushort8*)&Alds[srow * FBK + skq + h * 8] = pw;
    }
    __syncthreads();
#pragma unroll
    for (int ks = 0; ks < 2; ++ks) {
      short8 af[4]; short8 bfr[8];
#pragma unroll
      for (int fr = 0; fr < 4; ++fr)
        af[fr] = *(const short8*)&Alds[(wr * 64 + fr * 16 + l15) * FBK + ks * 32 + lk8];
#pragma unroll
      for (int fc = 0; fc < 8; ++fc)
        bfr[fc] = *(const short8*)&Blds[(wc * 128 + fc * 16 + l15) * FBK + ks * 32 + lk8];
#pragma unroll
      for (int fr = 0; fr < 4; ++fr)
#pragma unroll
        for (int fc = 0; fc < 8; ++fc)
          acc[fr][fc] =
              __builtin_amdgcn_mfma_f32_16x16x32_bf16(af[fr], bfr[fc], acc[fr][fc], 0, 0, 0);
    }
    __syncthreads();
  }
#pragma unroll
  for (int fr = 0; fr < 4; ++fr) {
    const int r0 = m0 + wr * 64 + fr * 16 + (lane >> 4) * 4;
#pragma unroll
    for (int fc = 0; fc < 8; ++fc) {
      const int col = wc * 128 + fc * 16 + l15;
#pragma unroll
      for (int j = 0; j < 4; ++j) {
        const int rr = r0 + j;
        if (rr < Ntot) out[(size_t)rr * O_DIM + col] = acc[fr][fc][j];
      }
    }
  }
}

extern "C" void kernel_launch(void* const* d_in, const int* in_sizes, int n_in,
                              void* d_out, int out_size, void* d_ws, size_t ws_size,
                              hipStream_t stream) {
  const float* x = (const float*)d_in[0];
  const float* e = (const float*)d_in[1];
  const float* W = (const float*)d_in[2];
  const float* b = (const float*)d_in[3];
  float* out = (float*)d_out;
  const int Ntot = in_sizes[0] / I_DIM;

  const size_t wb_bytes = (size_t)O_DIM * KEXT * sizeof(unsigned short);
  if (ws_size >= wb_bytes) {
    unsigned short* Wb = (unsigned short*)d_ws;
    prep_w<<<(O_DIM * (KEXT / 4)) / 256, 256, 0, stream>>>(W, b, Wb);
    const int nb = ((Ntot + BM - 1) / BM) * 2;
    lkg13<<<nb, NTHR, 0, stream>>>(x, e, Wb, out, Ntot);
  } else {
    lkg_fb<<<(Ntot + 127) / 128, 256, 0, stream>>>(x, e, W, b, out, Ntot);
  }
}

// Round 14
// 533.297 us; speedup vs baseline: 1.5608x; 1.5608x over previous
//
#include <hip/hip_runtime.h>
#include <hip/hip_bf16.h>

// y[n,o] = sum_r e[n,r]*(W[r]@x[n])[o] + (e@b)[n,o]
// bf16 GEMM, K = 8256, perm k = il*64 + rh*32 + ih*16 + rl (r = rh*16+rl,
// i = 128*ih + il), bias tile appended. Tile t == il.
// R14: A NEVER TOUCHES LDS. Each lane's A-frag (8-aligned k-run) has fixed (rh,ih):
// A-frag = bf16(x[n, ih*128+t] * e[n, 8-block]) -- e-block lane-constant across ALL
// tiles (32 f32 regs for 2 rows), x one scalar/tile/row. A-frags generated in VALU
// (co-issues under LDS-bound B path). LDS = B only, tri-buf 48 KB; ONE barrier/tile.
// 512 thr, 8 waves (4M x 2N), wave tile 32x64, acc[2][4]=32 AGPR;
// __launch_bounds__(512,4) pins 128-unified -> 2 blocks/CU, 16 waves/CU.

typedef __attribute__((ext_vector_type(4))) float f32x4;
typedef __attribute__((ext_vector_type(8))) short short8;
typedef __attribute__((ext_vector_type(8))) unsigned short ushort8;

#define R_DIM 32
#define I_DIM 256
#define O_DIM 256
#define KW    8192
#define KEXT  8256
#define BM    128
#define BNB   128             // per-block N (2 N-blocks cover O=256)
#define BK    64
#define NT    (KEXT / BK)     // 129
#define NTHR  512

__device__ __forceinline__ unsigned short f2bf(float f) {
  unsigned u = __builtin_bit_cast(unsigned, f);
  u += 0x7FFFu + ((u >> 16) & 1u);  // RNE
  return (unsigned short)(u >> 16);
}

__device__ __forceinline__ unsigned pk2(float a, float b) {
  __hip_bfloat162 h = __float22bfloat162_rn(make_float2(a, b));  // v_cvt_pk_bf16_f32
  unsigned u;
  __builtin_memcpy(&u, &h, sizeof(u));
  return u;
}

__device__ __forceinline__ void gld_lds16(const void* g, void* l) {
  __builtin_amdgcn_global_load_lds(
      (const __attribute__((address_space(1))) unsigned int*)g,
      (__attribute__((address_space(3))) unsigned int*)l, 16, 0, 0);
}

// ---- prep: Wb[o][k], k = il*64 + rh*32 + ih*16 + rl; bias block appended ----
__global__ void prep_w(const float* __restrict__ W, const float* __restrict__ b,
                       unsigned short* __restrict__ Wb) {
  const int id = blockIdx.x * 256 + threadIdx.x;   // 256 * 2064 threads exactly
  const int o  = id / (KEXT / 4);
  const int k4 = (id - o * (KEXT / 4)) * 4;
  float v[4];
  if (k4 < KW) {
    const int il = k4 >> 6;
    const int c  = k4 & 63;
    const int rh = c >> 5;
    const int ih = (c >> 4) & 1;
    const int rl = c & 15;
    const int i  = 128 * ih + il;
#pragma unroll
    for (int j = 0; j < 4; ++j)
      v[j] = W[((size_t)((rh * 16 + rl + j) * O_DIM + o)) * I_DIM + i];
  } else {
    const int c  = k4 - KW;
    const int ih = (c >> 4) & 1;
    const int rb = ((c >> 5) << 4) | (c & 15);
#pragma unroll
    for (int j = 0; j < 4; ++j)
      v[j] = (ih == 0) ? b[(rb + j) * O_DIM + o] : 0.f;
  }
  uint2 pk;
  pk.x = pk2(v[0], v[1]);
  pk.y = pk2(v[2], v[3]);
  *(uint2*)&Wb[(size_t)o * KEXT + k4] = pk;
}

// ---- main: 512 thr, 8 waves (4M x 2N), wave tile 32x64, B-only LDS ----
__global__ __launch_bounds__(NTHR, 4) void lkg14(
    const float* __restrict__ x, const float* __restrict__ e,
    const unsigned short* __restrict__ Wb, float* __restrict__ out, int Ntot) {
  __shared__ unsigned short Bl[3][BNB * BK];   // 3 x 16 KB = 48 KB -> 2+ blocks/CU

  const int tid  = threadIdx.x;
  const int lane = tid & 63;
  const int w    = tid >> 6;     // 0..7
  const int wr   = w >> 1;       // 0..3  (M, 32-row strips)
  const int wc   = w & 1;        // 0..1  (N, 64-col halves)
  const int l15  = lane & 15;
  const int lh   = lane >> 4;    // 0..3
  const int ih   = lh >> 1;      // x i-half this lane's A-slots use
  const int eb   = (lh & 1) * 8; // e col-block base
  const int sx   = (l15 & 7) << 4;
  const int kb0  = lh << 4;      // byte offset of lane's k-slot

  const int mi = (int)blockIdx.x >> 1;     // M-tile
  const int ni = (int)blockIdx.x & 1;      // N-half
  const int m0 = mi * BM;
  const unsigned short* WbN = Wb + (size_t)(ni * BNB) * KEXT;

  // B gld_lds source-side swizzle (rule #21: linear dest + inverse-swz source)
  const int bro = lane >> 3;
  const int bch = (lane & 7) ^ bro;

  // per-lane rows (fr = 0,1) and their e-blocks:
  // er[fr][ks*8+j] = e[row_fr, ks*16 + eb + j]   (constant for whole kernel)
  const int r0g = min(m0 + wr * 32 + 0 * 16 + l15, Ntot - 1);
  const int r1g = min(m0 + wr * 32 + 1 * 16 + l15, Ntot - 1);
  float er0[16], er1[16];
  {
    const float* b0 = e + (size_t)r0g * R_DIM;
    const float* b1 = e + (size_t)r1g * R_DIM;
#pragma unroll
    for (int q = 0; q < 2; ++q) {       // q = ks
      float4 fa = *(const float4*)(b0 + q * 16 + eb);
      float4 fb = *(const float4*)(b0 + q * 16 + eb + 4);
      er0[q * 8 + 0] = fa.x; er0[q * 8 + 1] = fa.y; er0[q * 8 + 2] = fa.z; er0[q * 8 + 3] = fa.w;
      er0[q * 8 + 4] = fb.x; er0[q * 8 + 5] = fb.y; er0[q * 8 + 6] = fb.z; er0[q * 8 + 7] = fb.w;
      fa = *(const float4*)(b1 + q * 16 + eb);
      fb = *(const float4*)(b1 + q * 16 + eb + 4);
      er1[q * 8 + 0] = fa.x; er1[q * 8 + 1] = fa.y; er1[q * 8 + 2] = fa.z; er1[q * 8 + 3] = fa.w;
      er1[q * 8 + 4] = fb.x; er1[q * 8 + 5] = fb.y; er1[q * 8 + 6] = fb.z; er1[q * 8 + 7] = fb.w;
    }
  }
  const float* xp0 = x + (size_t)r0g * I_DIM + ih * 128;  // x scalar stream, row fr=0
  const float* xp1 = x + (size_t)r1g * I_DIM + ih * 128;  // row fr=1

  f32x4 acc[2][4];
#pragma unroll
  for (int a = 0; a < 2; ++a)
#pragma unroll
    for (int c = 0; c < 4; ++c) acc[a][c] = (f32x4){0.f, 0.f, 0.f, 0.f};

  auto issueB2 = [&](unsigned short* Bd, int t2) {
    const size_t k0 = (size_t)t2 * BK;
#pragma unroll
    for (int g = 0; g < 2; ++g)
      gld_lds16(WbN + (size_t)(w * 16 + g * 8 + bro) * KEXT + k0 + bch * 8,
                Bd + (w * 16 + g * 8) * BK);
  };
  auto rdB = [&](const unsigned short* Bb, int ks, int fc) -> short8 {
    const int row = wc * 64 + fc * 16 + l15;
    return *(const short8*)((const char*)Bb + row * 128 + ((ks * 64 + kb0) ^ sx));
  };
  auto genA0 = [&](int ks, float xs) -> short8 {
    uint4 wv;
    wv.x = pk2(xs * er0[ks * 8 + 0], xs * er0[ks * 8 + 1]);
    wv.y = pk2(xs * er0[ks * 8 + 2], xs * er0[ks * 8 + 3]);
    wv.z = pk2(xs * er0[ks * 8 + 4], xs * er0[ks * 8 + 5]);
    wv.w = pk2(xs * er0[ks * 8 + 6], xs * er0[ks * 8 + 7]);
    short8 r;
    __builtin_memcpy(&r, &wv, 16);
    return r;
  };
  auto genA1 = [&](int ks, float xs) -> short8 {
    uint4 wv;
    wv.x = pk2(xs * er1[ks * 8 + 0], xs * er1[ks * 8 + 1]);
    wv.y = pk2(xs * er1[ks * 8 + 2], xs * er1[ks * 8 + 3]);
    wv.z = pk2(xs * er1[ks * 8 + 4], xs * er1[ks * 8 + 5]);
    wv.w = pk2(xs * er1[ks * 8 + 6], xs * er1[ks * 8 + 7]);
    short8 r;
    __builtin_memcpy(&r, &wv, 16);
    return r;
  };

  // one tile: issue B(t+2), read B-frags, gen A-frags in VALU, MFMA; 1 barrier.
  auto tileF = [&](int t, float xs0, float xs1, bool pre, int cb) {
    const unsigned short* Bc = Bl[cb];
    unsigned short*       Bw = Bl[cb >= 1 ? cb - 1 : 2];   // (cb+2)%3
    if (pre) issueB2(Bw, t + 2);

    short8 bf[4], af0, af1;
    // ks = 0
#pragma unroll
    for (int fc = 0; fc < 4; ++fc) bf[fc] = rdB(Bc, 0, fc);
    af0 = genA0(0, xs0);
    af1 = genA1(0, xs1);
    asm volatile("s_waitcnt lgkmcnt(0)" ::: "memory");
    __builtin_amdgcn_s_setprio(1);
#pragma unroll
    for (int fc = 0; fc < 4; ++fc) {
      acc[0][fc] = __builtin_amdgcn_mfma_f32_16x16x32_bf16(af0, bf[fc], acc[0][fc], 0, 0, 0);
      acc[1][fc] = __builtin_amdgcn_mfma_f32_16x16x32_bf16(af1, bf[fc], acc[1][fc], 0, 0, 0);
    }
    __builtin_amdgcn_s_setprio(0);
    // ks = 1
#pragma unroll
    for (int fc = 0; fc < 4; ++fc) bf[fc] = rdB(Bc, 1, fc);
    af0 = genA0(1, xs0);
    af1 = genA1(1, xs1);
    asm volatile("s_waitcnt lgkmcnt(0)" ::: "memory");
    __builtin_amdgcn_s_setprio(1);
#pragma unroll
    for (int fc = 0; fc < 4; ++fc) {
      acc[0][fc] = __builtin_amdgcn_mfma_f32_16x16x32_bf16(af0, bf[fc], acc[0][fc], 0, 0, 0);
      acc[1][fc] = __builtin_amdgcn_mfma_f32_16x16x32_bf16(af1, bf[fc], acc[1][fc], 0, 0, 0);
    }
    __builtin_amdgcn_s_setprio(0);
    if (pre) {
      asm volatile("s_waitcnt vmcnt(2)" ::: "memory");   // B(t+1) resident; B(t+2) in flight
    } else {
      asm volatile("s_waitcnt vmcnt(0)" ::: "memory");
    }
    __builtin_amdgcn_s_barrier();
  };

  // ---- prologue: B(0)->Bl[0], B(1)->Bl[1] ----
  issueB2(Bl[0], 0);
  issueB2(Bl[1], 1);
  float4 xv0 = *(const float4*)xp0;   // x scalars for tiles 0..3
  float4 xv1 = *(const float4*)xp1;
  asm volatile("s_waitcnt vmcnt(2)" ::: "memory");   // B(0) resident; B(1) in flight
  __builtin_amdgcn_s_barrier();

  int cb = 0;                                    // t % 3
  for (int u = 0; u < 32; ++u) {
    float4 xn0 = xv0, xn1 = xv1;
    if (u < 31) {
      xn0 = *(const float4*)(xp0 + (u + 1) * 4);
      xn1 = *(const float4*)(xp1 + (u + 1) * 4);
    }
    const int t0 = u * 4;
    tileF(t0 + 0, xv0.x, xv1.x, true, cb); cb = (cb == 2) ? 0 : cb + 1;
    tileF(t0 + 1, xv0.y, xv1.y, true, cb); cb = (cb == 2) ? 0 : cb + 1;
    tileF(t0 + 2, xv0.z, xv1.z, true, cb); cb = (cb == 2) ? 0 : cb + 1;
    tileF(t0 + 3, xv0.w, xv1.w, t0 + 3 < 127, cb); cb = (cb == 2) ? 0 : cb + 1;
    xv0 = xn0; xv1 = xn1;
  }
  // bias tile t=128: A' = e at ih=0 slots, 0 at ih=1 slots
  {
    const float bx = (ih == 0) ? 1.f : 0.f;
    tileF(128, bx, bx, false, cb);
  }

  // ---- epilogue: C layout col = lane&15, row = (lane>>4)*4 + j ----
#pragma unroll
  for (int fr = 0; fr < 2; ++fr) {
    const int r0 = m0 + wr * 32 + fr * 16 + (lane >> 4) * 4;
#pragma unroll
    for (int j = 0; j < 4; ++j) {
      const int rr = r0 + j;
      if (rr < Ntot) {
#pragma unroll
        for (int fc = 0; fc < 4; ++fc) {
          const int col = ni * BNB + wc * 64 + fc * 16 + l15;
          out[(size_t)rr * O_DIM + col] = acc[fr][fc][j];
        }
      }
    }
  }
}

// ---- fallback (ws too small): simple 2-barrier kernel reading W/b directly ----
__global__ __launch_bounds__(256) void lkg_fb(
    const float* __restrict__ x, const float* __restrict__ e,
    const float* __restrict__ Wf, const float* __restrict__ bf32,
    float* __restrict__ out, int Ntot) {
  const int FBK = 64;
  const int FNT = (KW + 64) / FBK;
  __shared__ unsigned short Alds[128 * 64];
  __shared__ unsigned short Blds[256 * 64];

  const int tid = threadIdx.x, lane = tid & 63, wid = tid >> 6;
  const int wr = wid >> 1, wc = wid & 1, l15 = lane & 15, lk8 = (lane >> 4) * 8;
  const int m0 = (int)blockIdx.x * 128;
  const int srow = tid >> 1, skq = (tid & 1) * 32;
  const int gr = min(m0 + srow, Ntot - 1);

  f32x4 acc[4][8];
#pragma unroll
  for (int a = 0; a < 4; ++a)
#pragma unroll
    for (int c = 0; c < 8; ++c) acc[a][c] = (f32x4){0.f, 0.f, 0.f, 0.f};

  for (int t = 0; t < FNT; ++t) {
    const int k0 = t * FBK;
    float av[32];
    if (k0 < KW) {
      const int r = k0 >> 8, i0 = k0 & 255;
      const float ev = e[(size_t)gr * R_DIM + r];
#pragma unroll
      for (int p = 0; p < 8; ++p) {
        const float4 xvv = *(const float4*)&x[(size_t)gr * I_DIM + i0 + skq + p * 4];
        av[p * 4 + 0] = xvv.x * ev; av[p * 4 + 1] = xvv.y * ev;
        av[p * 4 + 2] = xvv.z * ev; av[p * 4 + 3] = xvv.w * ev;
      }
    } else {
#pragma unroll
      for (int s2 = 0; s2 < 32; ++s2) {
        const int kk = skq + s2;
        av[s2] = (kk < R_DIM) ? e[(size_t)gr * R_DIM + kk] : 0.f;
      }
    }
    const int bo = tid;
    if (k0 < KW) {
      const int r = k0 >> 8, i0 = k0 & 255;
#pragma unroll
      for (int h = 0; h < 4; ++h) {
        float bv[16];
#pragma unroll
        for (int p = 0; p < 4; ++p) {
          const float4 wv =
              *(const float4*)&Wf[((size_t)(r * O_DIM + bo)) * I_DIM + i0 + h * 16 + p * 4];
          bv[p * 4 + 0] = wv.x; bv[p * 4 + 1] = wv.y;
          bv[p * 4 + 2] = wv.z; bv[p * 4 + 3] = wv.w;
        }
#pragma unroll
        for (int g2 = 0; g2 < 2; ++g2) {
          ushort8 pw;
#pragma unroll
          for (int j = 0; j < 8; ++j) pw[j] = f2bf(bv[g2 * 8 + j]);
          *(ushort8*)&Blds[bo * FBK + h * 16 + g2 * 8] = pw;
        }
      }
    } else {
#pragma unroll
      for (int h = 0; h < 8; ++h) {
        ushort8 pw;
#pragma unroll
        for (int j = 0; j < 8; ++j) {
          const int kk = h * 8 + j;
          pw[j] = (kk < R_DIM) ? f2bf(bf32[kk * O_DIM + bo]) : (unsigned short)0;
        }
        *(ushort8*)&Blds[bo * FBK + h * 8] = pw;
      }
    }
#pragma unroll
    for (int h = 0; h < 4; ++h) {
      ushort8 pw;
#pragma unroll
      for (int j = 0; j < 8; ++j) pw[j] = f2bf(av[h * 8 + j]);
      *(ushort8*)&Alds[srow * FBK + skq + h * 8] = pw;
    }
    __syncthreads();
#pragma unroll
    for (int ks = 0; ks < 2; ++ks) {
      short8 af[4]; short8 bfr[8];
#pragma unroll
      for (int fr = 0; fr < 4; ++fr)
        af[fr] = *(const short8*)&Alds[(wr * 64 + fr * 16 + l15) * FBK + ks * 32 + lk8];
#pragma unroll
      for (int fc = 0; fc < 8; ++fc)
        bfr[fc] = *(const short8*)&Blds[(wc * 128 + fc * 16 + l15) * FBK + ks * 32 + lk8];
#pragma unroll
      for (int fr = 0; fr < 4; ++fr)
#pragma unroll
        for (int fc = 0; fc < 8; ++fc)
          acc[fr][fc] =
              __builtin_amdgcn_mfma_f32_16x16x32_bf16(af[fr], bfr[fc], acc[fr][fc], 0, 0, 0);
    }
    __syncthreads();
  }
#pragma unroll
  for (int fr = 0; fr < 4; ++fr) {
    const int r0 = m0 + wr * 64 + fr * 16 + (lane >> 4) * 4;
#pragma unroll
    for (int fc = 0; fc < 8; ++fc) {
      const int col = wc * 128 + fc * 16 + l15;
#pragma unroll
      for (int j = 0; j < 4; ++j) {
        const int rr = r0 + j;
        if (rr < Ntot) out[(size_t)rr * O_DIM + col] = acc[fr][fc][j];
      }
    }
  }
}

extern "C" void kernel_launch(void* const* d_in, const int* in_sizes, int n_in,
                              void* d_out, int out_size, void* d_ws, size_t ws_size,
                              hipStream_t stream) {
  const float* x = (const float*)d_in[0];
  const float* e = (const float*)d_in[1];
  const float* W = (const float*)d_in[2];
  const float* b = (const float*)d_in[3];
  float* out = (float*)d_out;
  const int Ntot = in_sizes[0] / I_DIM;

  const size_t wb_bytes = (size_t)O_DIM * KEXT * sizeof(unsigned short);
  if (ws_size >= wb_bytes) {
    unsigned short* Wb = (unsigned short*)d_ws;
    prep_w<<<(O_DIM * (KEXT / 4)) / 256, 256, 0, stream>>>(W, b, Wb);
    const int nb = ((Ntot + BM - 1) / BM) * 2;
    lkg14<<<nb, NTHR, 0, stream>>>(x, e, Wb, out, Ntot);
  } else {
    lkg_fb<<<(Ntot + 127) / 128, 256, 0, stream>>>(x, e, W, b, out, Ntot);
  }
}